// Round 1
// baseline (147.604 us; speedup 1.0000x reference)
//
#include <hip/hip_runtime.h>
#include <cstdint>
#include <cstddef>

#define NCLS 19
#define HWSZ (512*1024)
#define NPIX (8*HWSZ)
#define OHEM_THRESH 0.7f
#define MIN_KEPT 100000u
#define IGNORE_L 255

// Workspace layout (zeroed by hipMemsetAsync each launch; ~25.7 KB)
struct Ws {
  double sum_all, sum_le, sum_fb;
  unsigned cnt_valid, cnt_le, cnt_fb;
  int mode;                 // 0: no-ohem (all valid), 1: threshold=0.7, 2: fallback exact-kth
  unsigned b1, r1, b2, r2;  // radix-select state
  float threshold;
  unsigned pad;
  unsigned hist1[2048];     // bits >> 20
  unsigned hist2[4096];     // (bits >> 8) & 0xFFF, given top bits == b1
  unsigned hist3[256];      // bits & 0xFF, given bits >> 8 == (b1<<12)|b2
};

__device__ __forceinline__ float f4c(const float4& v, int j) {
  return j == 0 ? v.x : j == 1 ? v.y : j == 2 ? v.z : v.w;
}
__device__ __forceinline__ int i4c(const int4& v, int j) {
  return j == 0 ? v.x : j == 1 ? v.y : j == 2 ? v.z : v.w;
}

// Scalar per-pixel log-softmax (fallback path only).
__device__ __forceinline__ void compute_px(const float* __restrict__ pr, int p, int label,
                                           float& nl, float& prd) {
  int n = p >> 19;            // / HWSZ
  int hw = p & (HWSZ - 1);
  const float* base = pr + (size_t)n * (NCLS * HWSZ) + hw;
  float x[NCLS];
#pragma unroll
  for (int c = 0; c < NCLS; ++c) x[c] = base[(size_t)c * HWSZ];
  float mx = -1e30f;
#pragma unroll
  for (int c = 0; c < NCLS; ++c) mx = fmaxf(mx, x[c]);
  float s = 0.f, tl = 0.f;
#pragma unroll
  for (int c = 0; c < NCLS; ++c) {
    s += __expf(x[c] - mx);
    if (c == label) tl = x[c];
  }
  float lse = mx + __logf(s);
  nl = lse - tl;
  prd = __expf(tl - lse);
}

// ---- main pass: one thread handles groups of 4 consecutive pixels (float4 loads) ----
__global__ __launch_bounds__(256) void k_main(const float* __restrict__ pr,
                                              const int* __restrict__ tg, Ws* ws) {
  const int ngroups = NPIX / 4;
  int tid = blockIdx.x * 256 + threadIdx.x;
  int stride = gridDim.x * 256;
  float s_all = 0.f, s_le = 0.f;
  unsigned c_valid = 0, c_le = 0;

  for (int gi = tid; gi < ngroups; gi += stride) {
    int p0 = gi * 4;
    int n = p0 >> 19;
    int hw = p0 & (HWSZ - 1);
    const float* base = pr + (size_t)n * (NCLS * HWSZ) + hw;
    float4 x[NCLS];
#pragma unroll
    for (int c = 0; c < NCLS; ++c)
      x[c] = *reinterpret_cast<const float4*>(base + (size_t)c * HWSZ);
    int4 lb = *reinterpret_cast<const int4*>(tg + p0);

#pragma unroll
    for (int j = 0; j < 4; ++j) {
      int label = i4c(lb, j);
      float mx = -1e30f;
#pragma unroll
      for (int c = 0; c < NCLS; ++c) mx = fmaxf(mx, f4c(x[c], j));
      float s = 0.f, tl = 0.f;
#pragma unroll
      for (int c = 0; c < NCLS; ++c) {
        float v = f4c(x[c], j);
        s += __expf(v - mx);
        if (c == label) tl = v;
      }
      float lse = mx + __logf(s);
      float nl = lse - tl;
      float prd = __expf(tl - lse);
      bool valid = (label != IGNORE_L);
      if (valid) {
        c_valid++;
        s_all += nl;
        if (prd <= OHEM_THRESH) { c_le++; s_le += nl; }
      }
    }
  }

  // block reduce: wave shfl then LDS across 4 waves
#pragma unroll
  for (int off = 32; off >= 1; off >>= 1) {
    s_all += __shfl_down(s_all, off);
    s_le += __shfl_down(s_le, off);
    c_valid += __shfl_down(c_valid, off);
    c_le += __shfl_down(c_le, off);
  }
  __shared__ float lsa[4], lsl[4];
  __shared__ unsigned lcv[4], lcl[4];
  int lane = threadIdx.x & 63, wv = threadIdx.x >> 6;
  if (lane == 0) { lsa[wv] = s_all; lsl[wv] = s_le; lcv[wv] = c_valid; lcl[wv] = c_le; }
  __syncthreads();
  if (threadIdx.x == 0) {
    float a = 0.f, b = 0.f;
    unsigned u = 0, v = 0;
    for (int i = 0; i < 4; ++i) { a += lsa[i]; b += lsl[i]; u += lcv[i]; v += lcl[i]; }
    atomicAdd(&ws->sum_all, (double)a);
    atomicAdd(&ws->sum_le, (double)b);
    atomicAdd(&ws->cnt_valid, u);
    atomicAdd(&ws->cnt_le, v);
  }
}

__global__ void k_decide(Ws* ws) {
  unsigned nv = ws->cnt_valid;
  bool do_ohem = (MIN_KEPT < nv) && (nv > 0);
  int mode;
  if (!do_ohem) mode = 0;
  else if (ws->cnt_le >= MIN_KEPT) mode = 1;  // kth smallest <= 0.7 -> threshold = 0.7
  else mode = 2;                              // need exact kth (> 0.7)
  ws->mode = mode;
}

// ---- fallback: 3-level radix select on float bits of pred (valid pixels only) ----
__global__ __launch_bounds__(256) void k_hist1(const float* __restrict__ pr,
                                               const int* __restrict__ tg, Ws* ws) {
  if (ws->mode != 2) return;
  __shared__ unsigned h[2048];
  for (int i = threadIdx.x; i < 2048; i += 256) h[i] = 0;
  __syncthreads();
  int tid = blockIdx.x * 256 + threadIdx.x;
  int stride = gridDim.x * 256;
  for (int p = tid; p < NPIX; p += stride) {
    int label = tg[p];
    if (label == IGNORE_L) continue;
    float nl, prd;
    compute_px(pr, p, label, nl, prd);
    atomicAdd(&h[__float_as_uint(prd) >> 20], 1u);
  }
  __syncthreads();
  for (int i = threadIdx.x; i < 2048; i += 256)
    if (h[i]) atomicAdd(&ws->hist1[i], h[i]);
}

__global__ __launch_bounds__(256) void k_scan1(Ws* ws) {
  if (ws->mode != 2) return;
  __shared__ unsigned part[256];
  const int per = 2048 / 256;
  unsigned s = 0;
  for (int i = 0; i < per; ++i) s += ws->hist1[threadIdx.x * per + i];
  part[threadIdx.x] = s;
  __syncthreads();
  if (threadIdx.x == 0) {
    unsigned k = MIN_KEPT - 1;  // mode 2 implies num_valid > MIN_KEPT
    unsigned run = 0; int seg = 0;
    for (int i = 0; i < 256; ++i) { if (run + part[i] > k) { seg = i; break; } run += part[i]; }
    unsigned r = k - run;
    for (int b = seg * per;; ++b) {
      unsigned hb = ws->hist1[b];
      if (r < hb) { ws->b1 = (unsigned)b; ws->r1 = r; break; }
      r -= hb;
    }
  }
}

__global__ __launch_bounds__(256) void k_hist2(const float* __restrict__ pr,
                                               const int* __restrict__ tg, Ws* ws) {
  if (ws->mode != 2) return;
  unsigned b1 = ws->b1;
  __shared__ unsigned h[4096];
  for (int i = threadIdx.x; i < 4096; i += 256) h[i] = 0;
  __syncthreads();
  int tid = blockIdx.x * 256 + threadIdx.x;
  int stride = gridDim.x * 256;
  for (int p = tid; p < NPIX; p += stride) {
    int label = tg[p];
    if (label == IGNORE_L) continue;
    float nl, prd;
    compute_px(pr, p, label, nl, prd);
    unsigned bits = __float_as_uint(prd);
    if ((bits >> 20) == b1) atomicAdd(&h[(bits >> 8) & 0xFFF], 1u);
  }
  __syncthreads();
  for (int i = threadIdx.x; i < 4096; i += 256)
    if (h[i]) atomicAdd(&ws->hist2[i], h[i]);
}

__global__ __launch_bounds__(256) void k_scan2(Ws* ws) {
  if (ws->mode != 2) return;
  __shared__ unsigned part[256];
  const int per = 4096 / 256;
  unsigned s = 0;
  for (int i = 0; i < per; ++i) s += ws->hist2[threadIdx.x * per + i];
  part[threadIdx.x] = s;
  __syncthreads();
  if (threadIdx.x == 0) {
    unsigned r = ws->r1;
    unsigned run = 0; int seg = 0;
    for (int i = 0; i < 256; ++i) { if (run + part[i] > r) { seg = i; break; } run += part[i]; }
    r -= run;
    for (int b = seg * per;; ++b) {
      unsigned hb = ws->hist2[b];
      if (r < hb) { ws->b2 = (unsigned)b; ws->r2 = r; break; }
      r -= hb;
    }
  }
}

__global__ __launch_bounds__(256) void k_hist3(const float* __restrict__ pr,
                                               const int* __restrict__ tg, Ws* ws) {
  if (ws->mode != 2) return;
  unsigned hi = (ws->b1 << 12) | ws->b2;
  __shared__ unsigned h[256];
  h[threadIdx.x] = 0;
  __syncthreads();
  int tid = blockIdx.x * 256 + threadIdx.x;
  int stride = gridDim.x * 256;
  for (int p = tid; p < NPIX; p += stride) {
    int label = tg[p];
    if (label == IGNORE_L) continue;
    float nl, prd;
    compute_px(pr, p, label, nl, prd);
    unsigned bits = __float_as_uint(prd);
    if ((bits >> 8) == hi) atomicAdd(&h[bits & 0xFF], 1u);
  }
  __syncthreads();
  if (h[threadIdx.x]) atomicAdd(&ws->hist3[threadIdx.x], h[threadIdx.x]);
}

__global__ __launch_bounds__(256) void k_scan3(Ws* ws) {
  if (ws->mode != 2) return;
  if (threadIdx.x == 0) {
    unsigned r = ws->r2;
    unsigned b3 = 0;
    for (int b = 0;; ++b) {
      unsigned hb = ws->hist3[b];
      if (r < hb) { b3 = (unsigned)b; break; }
      r -= hb;
    }
    float thr = __uint_as_float((ws->b1 << 20) | (ws->b2 << 8) | b3);
    ws->threshold = (thr > OHEM_THRESH) ? thr : OHEM_THRESH;
  }
}

__global__ __launch_bounds__(256) void k_sumfb(const float* __restrict__ pr,
                                               const int* __restrict__ tg, Ws* ws) {
  if (ws->mode != 2) return;
  float thr = ws->threshold;
  float s_fb = 0.f;
  unsigned c_fb = 0;
  int tid = blockIdx.x * 256 + threadIdx.x;
  int stride = gridDim.x * 256;
  for (int p = tid; p < NPIX; p += stride) {
    int label = tg[p];
    if (label == IGNORE_L) continue;
    float nl, prd;
    compute_px(pr, p, label, nl, prd);
    if (prd <= thr) { c_fb++; s_fb += nl; }
  }
#pragma unroll
  for (int off = 32; off >= 1; off >>= 1) {
    s_fb += __shfl_down(s_fb, off);
    c_fb += __shfl_down(c_fb, off);
  }
  __shared__ float lsf[4];
  __shared__ unsigned lcf[4];
  int lane = threadIdx.x & 63, wv = threadIdx.x >> 6;
  if (lane == 0) { lsf[wv] = s_fb; lcf[wv] = c_fb; }
  __syncthreads();
  if (threadIdx.x == 0) {
    float a = 0.f; unsigned u = 0;
    for (int i = 0; i < 4; ++i) { a += lsf[i]; u += lcf[i]; }
    atomicAdd(&ws->sum_fb, (double)a);
    atomicAdd(&ws->cnt_fb, u);
  }
}

__global__ void k_final(Ws* ws, float* out) {
  int mode = ws->mode;
  double s; unsigned c;
  if (mode == 0) { s = ws->sum_all; c = ws->cnt_valid; }
  else if (mode == 1) { s = ws->sum_le; c = ws->cnt_le; }
  else { s = ws->sum_fb; c = ws->cnt_fb; }
  unsigned cc = c > 0 ? c : 1;
  out[0] = (float)(s / (double)cc);
}

extern "C" void kernel_launch(void* const* d_in, const int* in_sizes, int n_in,
                              void* d_out, int out_size, void* d_ws, size_t ws_size,
                              hipStream_t stream) {
  const float* pr = (const float*)d_in[0];
  const int* tg = (const int*)d_in[1];
  float* out = (float*)d_out;
  Ws* ws = (Ws*)d_ws;

  hipMemsetAsync(d_ws, 0, sizeof(Ws), stream);
  k_main<<<2048, 256, 0, stream>>>(pr, tg, ws);
  k_decide<<<1, 1, 0, stream>>>(ws);
  k_hist1<<<1024, 256, 0, stream>>>(pr, tg, ws);
  k_scan1<<<1, 256, 0, stream>>>(ws);
  k_hist2<<<1024, 256, 0, stream>>>(pr, tg, ws);
  k_scan2<<<1, 256, 0, stream>>>(ws);
  k_hist3<<<1024, 256, 0, stream>>>(pr, tg, ws);
  k_scan3<<<1, 256, 0, stream>>>(ws);
  k_sumfb<<<1024, 256, 0, stream>>>(pr, tg, ws);
  k_final<<<1, 1, 0, stream>>>(ws, out);
}

// Round 2
// 83.030 us; speedup vs baseline: 1.7777x; 1.7777x over previous
//
#include <hip/hip_runtime.h>
#include <cstdint>
#include <cstddef>

#define NCLS 19
#define HWSZ (512*1024)
#define NPIX (8*HWSZ)
#define NGROUPS (NPIX/4)
#define MAIN_BLOCKS (NGROUPS/256)   // 4096
#define FB_BLOCKS 256
#define OHEM_THRESH 0.7f
#define KEEP_NL 0.35667494f         // -ln(0.7): pred <= 0.7  <=>  nl >= KEEP_NL
#define MIN_KEPT 100000u
#define IGNORE_L 255

struct alignas(16) Partial { float sa, sl; unsigned cv, cl; };

// Workspace (~90 KB). No memset needed: everything is written before read
// on every call (k_decide zeroes the mode-2-only structures when mode==2).
struct Ws {
  double sum_all, sum_le, sum_fb;
  unsigned cnt_valid, cnt_le, cnt_fb;
  int mode;                  // 0: keep all valid, 1: threshold = 0.7, 2: exact kth (fallback)
  unsigned hist1[2048];      // pred float bits >> 20
  unsigned hist2[4096];      // (bits >> 8) & 0xFFF  | top == b1
  unsigned hist3[256];       // bits & 0xFF          | bits>>8 == (b1<<12)|b2
  Partial partials[MAIN_BLOCKS];
};

// ---------------- main pass: online softmax, 4 pixels/thread ----------------
__global__ __launch_bounds__(256) void k_main(const float* __restrict__ pr,
                                              const int* __restrict__ tg,
                                              Ws* __restrict__ ws) {
  int gi = blockIdx.x * 256 + threadIdx.x;       // exactly NGROUPS threads
  int p0 = gi * 4;
  int n = p0 >> 19;                               // / HWSZ
  int hw = p0 & (HWSZ - 1);
  const float* base = pr + (size_t)n * (NCLS * HWSZ) + hw;
  int4 lb = *reinterpret_cast<const int4*>(tg + p0);
  int lbl[4] = {lb.x, lb.y, lb.z, lb.w};

  float m[4], s[4], t[4];
#pragma unroll
  for (int j = 0; j < 4; ++j) { m[j] = -1e30f; s[j] = 0.f; t[j] = 0.f; }

#pragma unroll
  for (int c = 0; c < NCLS; ++c) {
    float4 x = *reinterpret_cast<const float4*>(base + (size_t)c * HWSZ);
    float v[4] = {x.x, x.y, x.z, x.w};
#pragma unroll
    for (int j = 0; j < 4; ++j) {
      float nm = fmaxf(m[j], v[j]);
      s[j] = s[j] * __expf(m[j] - nm) + __expf(v[j] - nm);
      m[j] = nm;
      t[j] = (c == lbl[j]) ? v[j] : t[j];
    }
  }

  float s_all = 0.f, s_le = 0.f;
  unsigned c_valid = 0, c_le = 0;
#pragma unroll
  for (int j = 0; j < 4; ++j) {
    float lse = m[j] + __logf(s[j]);
    float nl = lse - t[j];
    if (lbl[j] != IGNORE_L) {
      c_valid++; s_all += nl;
      if (nl >= KEEP_NL) { c_le++; s_le += nl; }
    }
  }

#pragma unroll
  for (int off = 32; off >= 1; off >>= 1) {
    s_all   += __shfl_down(s_all, off);
    s_le    += __shfl_down(s_le, off);
    c_valid += __shfl_down(c_valid, off);
    c_le    += __shfl_down(c_le, off);
  }
  __shared__ float lsa[4], lsl[4];
  __shared__ unsigned lcv[4], lcl[4];
  int lane = threadIdx.x & 63, wv = threadIdx.x >> 6;
  if (lane == 0) { lsa[wv] = s_all; lsl[wv] = s_le; lcv[wv] = c_valid; lcl[wv] = c_le; }
  __syncthreads();
  if (threadIdx.x == 0) {
    Partial p;
    p.sa = lsa[0] + lsa[1] + lsa[2] + lsa[3];
    p.sl = lsl[0] + lsl[1] + lsl[2] + lsl[3];
    p.cv = lcv[0] + lcv[1] + lcv[2] + lcv[3];
    p.cl = lcl[0] + lcl[1] + lcl[2] + lcl[3];
    ws->partials[blockIdx.x] = p;
  }
}

// ---------------- reduce partials + decide mode ----------------
__global__ __launch_bounds__(256) void k_decide(Ws* __restrict__ ws) {
  int tid = threadIdx.x;
  double sa = 0.0, sl = 0.0;
  unsigned long long cv = 0, cl = 0;
  for (int i = tid; i < MAIN_BLOCKS; i += 256) {
    Partial p = ws->partials[i];
    sa += (double)p.sa; sl += (double)p.sl; cv += p.cv; cl += p.cl;
  }
  __shared__ double dsa[256], dsl[256];
  __shared__ unsigned long long dcv[256], dcl[256];
  dsa[tid] = sa; dsl[tid] = sl; dcv[tid] = cv; dcl[tid] = cl;
  __syncthreads();
  for (int st = 128; st > 0; st >>= 1) {
    if (tid < st) {
      dsa[tid] += dsa[tid + st]; dsl[tid] += dsl[tid + st];
      dcv[tid] += dcv[tid + st]; dcl[tid] += dcl[tid + st];
    }
    __syncthreads();
  }
  __shared__ int smode;
  if (tid == 0) {
    unsigned nv = (unsigned)dcv[0], nle = (unsigned)dcl[0];
    ws->sum_all = dsa[0]; ws->sum_le = dsl[0];
    ws->cnt_valid = nv; ws->cnt_le = nle;
    int mode = (nv > MIN_KEPT) ? ((nle >= MIN_KEPT) ? 1 : 2) : 0;
    ws->mode = mode; smode = mode;
    if (mode == 2) { ws->sum_fb = 0.0; ws->cnt_fb = 0; }
  }
  __syncthreads();
  if (smode == 2) {
    for (int i = tid; i < 2048; i += 256) ws->hist1[i] = 0;
    for (int i = tid; i < 4096; i += 256) ws->hist2[i] = 0;
    ws->hist3[tid] = 0;
  }
}

// ---------------- fallback path (mode 2 only; never hot for this input) ----------------
__device__ __forceinline__ void compute_px(const float* __restrict__ pr, int p, int label,
                                           float& nl, float& prd) {
  int n = p >> 19;
  int hw = p & (HWSZ - 1);
  const float* base = pr + (size_t)n * (NCLS * HWSZ) + hw;
  float x[NCLS];
#pragma unroll
  for (int c = 0; c < NCLS; ++c) x[c] = base[(size_t)c * HWSZ];
  float mx = -1e30f;
#pragma unroll
  for (int c = 0; c < NCLS; ++c) mx = fmaxf(mx, x[c]);
  float s = 0.f, tl = 0.f;
#pragma unroll
  for (int c = 0; c < NCLS; ++c) {
    s += __expf(x[c] - mx);
    if (c == label) tl = x[c];
  }
  float lse = mx + __logf(s);
  nl = lse - tl;
  prd = __expf(tl - lse);
}

__device__ __forceinline__ void scan_hist(const unsigned* __restrict__ h, int nb,
                                          unsigned r_in, unsigned& b_out, unsigned& r_out) {
  unsigned r = r_in;
  for (int b = 0; b < nb; ++b) {
    unsigned hb = h[b];
    if (r < hb) { b_out = (unsigned)b; r_out = r; return; }
    r -= hb;
  }
  b_out = (unsigned)(nb - 1); r_out = 0;
}

__global__ __launch_bounds__(256) void k_h1(const float* __restrict__ pr,
                                            const int* __restrict__ tg, Ws* ws) {
  if (ws->mode != 2) return;
  __shared__ unsigned h[2048];
  for (int i = threadIdx.x; i < 2048; i += 256) h[i] = 0;
  __syncthreads();
  int tid = blockIdx.x * 256 + threadIdx.x;
  for (int p = tid; p < NPIX; p += FB_BLOCKS * 256) {
    int label = tg[p];
    if (label == IGNORE_L) continue;
    float nl, prd;
    compute_px(pr, p, label, nl, prd);
    atomicAdd(&h[__float_as_uint(prd) >> 20], 1u);
  }
  __syncthreads();
  for (int i = threadIdx.x; i < 2048; i += 256)
    if (h[i]) atomicAdd(&ws->hist1[i], h[i]);
}

__global__ __launch_bounds__(256) void k_h2(const float* __restrict__ pr,
                                            const int* __restrict__ tg, Ws* ws) {
  if (ws->mode != 2) return;
  __shared__ unsigned h[4096];
  __shared__ unsigned sb1;
  if (threadIdx.x == 0) { unsigned b, r; scan_hist(ws->hist1, 2048, MIN_KEPT - 1, b, r); sb1 = b; }
  for (int i = threadIdx.x; i < 4096; i += 256) h[i] = 0;
  __syncthreads();
  unsigned b1 = sb1;
  int tid = blockIdx.x * 256 + threadIdx.x;
  for (int p = tid; p < NPIX; p += FB_BLOCKS * 256) {
    int label = tg[p];
    if (label == IGNORE_L) continue;
    float nl, prd;
    compute_px(pr, p, label, nl, prd);
    unsigned bits = __float_as_uint(prd);
    if ((bits >> 20) == b1) atomicAdd(&h[(bits >> 8) & 0xFFF], 1u);
  }
  __syncthreads();
  for (int i = threadIdx.x; i < 4096; i += 256)
    if (h[i]) atomicAdd(&ws->hist2[i], h[i]);
}

__global__ __launch_bounds__(256) void k_h3(const float* __restrict__ pr,
                                            const int* __restrict__ tg, Ws* ws) {
  if (ws->mode != 2) return;
  __shared__ unsigned h[256];
  __shared__ unsigned shi;
  if (threadIdx.x == 0) {
    unsigned b1, r1, b2, r2;
    scan_hist(ws->hist1, 2048, MIN_KEPT - 1, b1, r1);
    scan_hist(ws->hist2, 4096, r1, b2, r2);
    shi = (b1 << 12) | b2;
  }
  h[threadIdx.x] = 0;
  __syncthreads();
  unsigned hi = shi;
  int tid = blockIdx.x * 256 + threadIdx.x;
  for (int p = tid; p < NPIX; p += FB_BLOCKS * 256) {
    int label = tg[p];
    if (label == IGNORE_L) continue;
    float nl, prd;
    compute_px(pr, p, label, nl, prd);
    unsigned bits = __float_as_uint(prd);
    if ((bits >> 8) == hi) atomicAdd(&h[bits & 0xFF], 1u);
  }
  __syncthreads();
  if (h[threadIdx.x]) atomicAdd(&ws->hist3[threadIdx.x], h[threadIdx.x]);
}

__global__ __launch_bounds__(256) void k_sumfb(const float* __restrict__ pr,
                                               const int* __restrict__ tg, Ws* ws) {
  if (ws->mode != 2) return;
  __shared__ float sthr;
  if (threadIdx.x == 0) {
    unsigned b1, r1, b2, r2, b3, r3;
    scan_hist(ws->hist1, 2048, MIN_KEPT - 1, b1, r1);
    scan_hist(ws->hist2, 4096, r1, b2, r2);
    scan_hist(ws->hist3, 256, r2, b3, r3);
    float thr = __uint_as_float((b1 << 20) | (b2 << 8) | b3);
    sthr = (thr > OHEM_THRESH) ? thr : OHEM_THRESH;
  }
  __syncthreads();
  float thr = sthr;
  float s_fb = 0.f;
  unsigned c_fb = 0;
  int tid = blockIdx.x * 256 + threadIdx.x;
  for (int p = tid; p < NPIX; p += FB_BLOCKS * 256) {
    int label = tg[p];
    if (label == IGNORE_L) continue;
    float nl, prd;
    compute_px(pr, p, label, nl, prd);
    if (prd <= thr) { c_fb++; s_fb += nl; }
  }
#pragma unroll
  for (int off = 32; off >= 1; off >>= 1) {
    s_fb += __shfl_down(s_fb, off);
    c_fb += __shfl_down(c_fb, off);
  }
  __shared__ float lsf[4];
  __shared__ unsigned lcf[4];
  int lane = threadIdx.x & 63, wv = threadIdx.x >> 6;
  if (lane == 0) { lsf[wv] = s_fb; lcf[wv] = c_fb; }
  __syncthreads();
  if (threadIdx.x == 0) {
    float a = lsf[0] + lsf[1] + lsf[2] + lsf[3];
    unsigned u = lcf[0] + lcf[1] + lcf[2] + lcf[3];
    atomicAdd(&ws->sum_fb, (double)a);
    atomicAdd(&ws->cnt_fb, u);
  }
}

__global__ void k_final(Ws* __restrict__ ws, float* __restrict__ out) {
  int mode = ws->mode;
  double s; unsigned c;
  if (mode == 0)      { s = ws->sum_all; c = ws->cnt_valid; }
  else if (mode == 1) { s = ws->sum_le;  c = ws->cnt_le; }
  else                { s = ws->sum_fb;  c = ws->cnt_fb; }
  unsigned cc = c > 0 ? c : 1;
  out[0] = (float)(s / (double)cc);
}

extern "C" void kernel_launch(void* const* d_in, const int* in_sizes, int n_in,
                              void* d_out, int out_size, void* d_ws, size_t ws_size,
                              hipStream_t stream) {
  const float* pr = (const float*)d_in[0];
  const int* tg = (const int*)d_in[1];
  float* out = (float*)d_out;
  Ws* ws = (Ws*)d_ws;

  k_main<<<MAIN_BLOCKS, 256, 0, stream>>>(pr, tg, ws);
  k_decide<<<1, 256, 0, stream>>>(ws);
  k_h1<<<FB_BLOCKS, 256, 0, stream>>>(pr, tg, ws);
  k_h2<<<FB_BLOCKS, 256, 0, stream>>>(pr, tg, ws);
  k_h3<<<FB_BLOCKS, 256, 0, stream>>>(pr, tg, ws);
  k_sumfb<<<FB_BLOCKS, 256, 0, stream>>>(pr, tg, ws);
  k_final<<<1, 1, 0, stream>>>(ws, out);
}

// Round 4
// 64.736 us; speedup vs baseline: 2.2801x; 1.2826x over previous
//
#include <hip/hip_runtime.h>
#include <cstdint>
#include <cstddef>

#define NCLS 19
#define HWSZ (512*1024)
#define NPIX (8*HWSZ)
#define NGROUPS (NPIX/4)
#define MAIN_BLOCKS (NGROUPS/256)   // 4096
#define TAIL_THREADS 1024
#define OHEM_THRESH 0.7f
#define KEEP_NL 0.35667494f         // -ln(0.7): pred <= 0.7  <=>  nl >= KEEP_NL
#define MIN_KEPT 100000u
#define IGNORE_L 255

typedef float f32x4 __attribute__((ext_vector_type(4)));
typedef int   i32x4 __attribute__((ext_vector_type(4)));

struct alignas(16) Partial { float sa, sl; unsigned cv, cl; };

// Workspace: only per-block partials (fully written by k_main before k_tail
// reads them on every call — no init needed, poison-safe).
struct Ws {
  Partial partials[MAIN_BLOCKS];    // 64 KB
};

// ---------------- main pass: online softmax (1 exp/class), 4 pixels/thread ----------------
__global__ __launch_bounds__(256) void k_main(const float* __restrict__ pr,
                                              const int* __restrict__ tg,
                                              Ws* __restrict__ ws) {
  int gi = blockIdx.x * 256 + threadIdx.x;       // exactly NGROUPS threads
  int p0 = gi * 4;
  int n = p0 >> 19;                               // / HWSZ
  int hw = p0 & (HWSZ - 1);
  const float* base = pr + (size_t)n * (NCLS * HWSZ) + hw;
  i32x4 lb = *reinterpret_cast<const i32x4*>(tg + p0);
  int lbl[4] = {lb.x, lb.y, lb.z, lb.w};

  float m[4], s[4], t[4];
#pragma unroll
  for (int j = 0; j < 4; ++j) { m[j] = -1e30f; s[j] = 0.f; t[j] = 0.f; }

#pragma unroll
  for (int c = 0; c < NCLS; ++c) {
    const f32x4* src = reinterpret_cast<const f32x4*>(base + (size_t)c * HWSZ);
    f32x4 x = __builtin_nontemporal_load(src);
    float v[4] = {x.x, x.y, x.z, x.w};
#pragma unroll
    for (int j = 0; j < 4; ++j) {
      float nm = fmaxf(m[j], v[j]);
      float e  = __expf(fminf(m[j], v[j]) - nm);   // one exp; the other factor is exp(0)=1
      s[j] = (v[j] > m[j]) ? __fmaf_rn(s[j], e, 1.f) : (s[j] + e);
      m[j] = nm;
      t[j] = (c == lbl[j]) ? v[j] : t[j];
    }
  }

  float s_all = 0.f, s_le = 0.f;
  unsigned c_valid = 0, c_le = 0;
#pragma unroll
  for (int j = 0; j < 4; ++j) {
    float lse = m[j] + __logf(s[j]);
    float nl = lse - t[j];
    if (lbl[j] != IGNORE_L) {
      c_valid++; s_all += nl;
      if (nl >= KEEP_NL) { c_le++; s_le += nl; }
    }
  }

#pragma unroll
  for (int off = 32; off >= 1; off >>= 1) {
    s_all   += __shfl_down(s_all, off);
    s_le    += __shfl_down(s_le, off);
    c_valid += __shfl_down(c_valid, off);
    c_le    += __shfl_down(c_le, off);
  }
  __shared__ float lsa[4], lsl[4];
  __shared__ unsigned lcv[4], lcl[4];
  int lane = threadIdx.x & 63, wv = threadIdx.x >> 6;
  if (lane == 0) { lsa[wv] = s_all; lsl[wv] = s_le; lcv[wv] = c_valid; lcl[wv] = c_le; }
  __syncthreads();
  if (threadIdx.x == 0) {
    Partial p;
    p.sa = lsa[0] + lsa[1] + lsa[2] + lsa[3];
    p.sl = lsl[0] + lsl[1] + lsl[2] + lsl[3];
    p.cv = lcv[0] + lcv[1] + lcv[2] + lcv[3];
    p.cl = lcl[0] + lcl[1] + lcl[2] + lcl[3];
    ws->partials[blockIdx.x] = p;
  }
}

// ---------------- single-block tail: reduce + decide + (mode-2 radix select) + finalize ----
__device__ __forceinline__ void compute_px(const float* __restrict__ pr, int p, int label,
                                           float& nl, float& prd) {
  int n = p >> 19;
  int hw = p & (HWSZ - 1);
  const float* base = pr + (size_t)n * (NCLS * HWSZ) + hw;
  float x[NCLS];
#pragma unroll
  for (int c = 0; c < NCLS; ++c) x[c] = base[(size_t)c * HWSZ];
  float mx = -1e30f;
#pragma unroll
  for (int c = 0; c < NCLS; ++c) mx = fmaxf(mx, x[c]);
  float s = 0.f, tl = 0.f;
#pragma unroll
  for (int c = 0; c < NCLS; ++c) {
    s += __expf(x[c] - mx);
    if (c == label) tl = x[c];
  }
  float lse = mx + __logf(s);
  nl = lse - tl;
  prd = __expf(tl - lse);
}

__device__ __forceinline__ void scan_hist_lds(const unsigned* h, int nb,
                                              unsigned r_in, unsigned& b_out, unsigned& r_out) {
  unsigned r = r_in;
  for (int b = 0; b < nb; ++b) {
    unsigned hb = h[b];
    if (r < hb) { b_out = (unsigned)b; r_out = r; return; }
    r -= hb;
  }
  b_out = (unsigned)(nb - 1); r_out = 0;
}

__global__ __launch_bounds__(TAIL_THREADS) void k_tail(const float* __restrict__ pr,
                                                       const int* __restrict__ tg,
                                                       Ws* __restrict__ ws,
                                                       float* __restrict__ out) {
  __shared__ double dsa[TAIL_THREADS], dsl[TAIL_THREADS];
  __shared__ unsigned long long dcv[TAIL_THREADS], dcl[TAIL_THREADS];
  int tid = threadIdx.x;

  double sa = 0.0, sl = 0.0;
  unsigned long long cv = 0, cl = 0;
  for (int i = tid; i < MAIN_BLOCKS; i += TAIL_THREADS) {
    Partial p = ws->partials[i];
    sa += (double)p.sa; sl += (double)p.sl; cv += p.cv; cl += p.cl;
  }
  dsa[tid] = sa; dsl[tid] = sl; dcv[tid] = cv; dcl[tid] = cl;
  __syncthreads();
  for (int st = TAIL_THREADS / 2; st > 0; st >>= 1) {
    if (tid < st) {
      dsa[tid] += dsa[tid + st]; dsl[tid] += dsl[tid + st];
      dcv[tid] += dcv[tid + st]; dcl[tid] += dcl[tid + st];
    }
    __syncthreads();
  }

  __shared__ int smode;
  if (tid == 0) {
    unsigned nv = (unsigned)dcv[0], nle = (unsigned)dcl[0];
    int mode = (nv > MIN_KEPT) ? ((nle >= MIN_KEPT) ? 1 : 2) : 0;
    smode = mode;
    if (mode == 0) {
      unsigned cc = nv > 0 ? nv : 1;
      out[0] = (float)(dsa[0] / (double)cc);
    } else if (mode == 1) {
      unsigned cc = nle > 0 ? nle : 1;
      out[0] = (float)(dsl[0] / (double)cc);
    }
  }
  __syncthreads();
  if (smode != 2) return;   // uniform branch

  // ---- mode 2 (never hot for this input): exact kth via 3-level radix select, one block ----
  __shared__ unsigned h1[2048], h2[4096], h3[256];
  __shared__ unsigned sb1, sr1, sb2, sr2;
  __shared__ float sthr;

  for (int i = tid; i < 2048; i += TAIL_THREADS) h1[i] = 0;
  __syncthreads();
  for (int p = tid; p < NPIX; p += TAIL_THREADS) {
    int label = tg[p];
    if (label == IGNORE_L) continue;
    float nl, prd;
    compute_px(pr, p, label, nl, prd);
    atomicAdd(&h1[__float_as_uint(prd) >> 20], 1u);
  }
  __syncthreads();
  if (tid == 0) { unsigned b, r; scan_hist_lds(h1, 2048, MIN_KEPT - 1, b, r); sb1 = b; sr1 = r; }
  __syncthreads();

  for (int i = tid; i < 4096; i += TAIL_THREADS) h2[i] = 0;
  __syncthreads();
  {
    unsigned b1 = sb1;
    for (int p = tid; p < NPIX; p += TAIL_THREADS) {
      int label = tg[p];
      if (label == IGNORE_L) continue;
      float nl, prd;
      compute_px(pr, p, label, nl, prd);
      unsigned bits = __float_as_uint(prd);
      if ((bits >> 20) == b1) atomicAdd(&h2[(bits >> 8) & 0xFFF], 1u);
    }
  }
  __syncthreads();
  if (tid == 0) { unsigned b, r; scan_hist_lds(h2, 4096, sr1, b, r); sb2 = b; sr2 = r; }
  __syncthreads();

  for (int i = tid; i < 256; i += TAIL_THREADS) h3[i] = 0;
  __syncthreads();
  {
    unsigned hi = (sb1 << 12) | sb2;
    for (int p = tid; p < NPIX; p += TAIL_THREADS) {
      int label = tg[p];
      if (label == IGNORE_L) continue;
      float nl, prd;
      compute_px(pr, p, label, nl, prd);
      unsigned bits = __float_as_uint(prd);
      if ((bits >> 8) == hi) atomicAdd(&h3[bits & 0xFF], 1u);
    }
  }
  __syncthreads();
  if (tid == 0) {
    unsigned b3, r3;
    scan_hist_lds(h3, 256, sr2, b3, r3);
    float thr = __uint_as_float((sb1 << 20) | (sb2 << 8) | b3);
    sthr = (thr > OHEM_THRESH) ? thr : OHEM_THRESH;
  }
  __syncthreads();

  {
    float thr = sthr;
    double s_fb = 0.0;
    unsigned long long c_fb = 0;
    for (int p = tid; p < NPIX; p += TAIL_THREADS) {
      int label = tg[p];
      if (label == IGNORE_L) continue;
      float nl, prd;
      compute_px(pr, p, label, nl, prd);
      if (prd <= thr) { c_fb++; s_fb += (double)nl; }
    }
    dsa[tid] = s_fb; dcv[tid] = c_fb;
    __syncthreads();
    for (int st = TAIL_THREADS / 2; st > 0; st >>= 1) {
      if (tid < st) { dsa[tid] += dsa[tid + st]; dcv[tid] += dcv[tid + st]; }
      __syncthreads();
    }
    if (tid == 0) {
      unsigned long long c = dcv[0];
      unsigned long long cc = c > 0 ? c : 1;
      out[0] = (float)(dsa[0] / (double)cc);
    }
  }
}

extern "C" void kernel_launch(void* const* d_in, const int* in_sizes, int n_in,
                              void* d_out, int out_size, void* d_ws, size_t ws_size,
                              hipStream_t stream) {
  const float* pr = (const float*)d_in[0];
  const int* tg = (const int*)d_in[1];
  float* out = (float*)d_out;
  Ws* ws = (Ws*)d_ws;

  k_main<<<MAIN_BLOCKS, 256, 0, stream>>>(pr, tg, ws);
  k_tail<<<1, TAIL_THREADS, 0, stream>>>(pr, tg, ws, out);
}